// Round 11
// baseline (322.786 us; speedup 1.0000x reference)
//
#include <hip/hip_runtime.h>
#include <stdint.h>

#define DIM   2048
#define NH    32
#define NKV   8
#define HD    64
#define BATCH 2
#define SEQ   2048

typedef __attribute__((ext_vector_type(8))) short  short8;
typedef __attribute__((ext_vector_type(4))) short  short4v;
typedef __attribute__((ext_vector_type(4))) float  f32x4;

#if __has_builtin(__builtin_amdgcn_exp2f)
#define EXP2(x) __builtin_amdgcn_exp2f(x)
#else
#define EXP2(x) exp2f(x)
#endif

static __device__ __forceinline__ short f2bf(float f) {
  union { float f; uint32_t u; } v; v.f = f;
  uint32_t r = v.u + 0x7FFFu + ((v.u >> 16) & 1u);
  return (short)(r >> 16);
}

static __device__ __forceinline__ uint32_t cvtpk_bf16(float lo, float hi) {
  uint32_t r;
  asm("v_cvt_pk_bf16_f32 %0, %1, %2" : "=v"(r) : "v"(lo), "v"(hi));
  return r;
}

#define GLD16(gp, lp) __builtin_amdgcn_global_load_lds(                      \
    (__attribute__((address_space(1))) void*)(void*)(gp),                    \
    (__attribute__((address_space(3))) void*)(lp), 16, 0, 0)

// log2(e) * (1/sqrt(HD))  folded into Q at projection time
#define QSCALE 0.1803368801111244f

// ---------------- fused prep: cvt_x + w transposes + rope table ----------------
__global__ void __launch_bounds__(256)
prep_kernel(const float* __restrict__ x, const float* __restrict__ wq,
            const float* __restrict__ wk, const float* __restrict__ wv,
            const float* __restrict__ wo,
            short* __restrict__ x_bf, short* __restrict__ wq_t,
            short* __restrict__ wk_t, short* __restrict__ wv_t,
            short* __restrict__ wo_t,
            float* __restrict__ ct, float* __restrict__ st) {
  __shared__ float t[32][33];
  int blk = blockIdx.x;
  const int tid = threadIdx.x;
  if (blk < 8192) {
    int i = blk * 256 + tid;
    f32x4 v = *reinterpret_cast<const f32x4*>(x + (size_t)i * 4);
    short4v o;
    o.x = f2bf(v.x); o.y = f2bf(v.y); o.z = f2bf(v.z); o.w = f2bf(v.w);
    *reinterpret_cast<short4v*>(x_bf + (size_t)i * 4) = o;
    return;
  }
  blk -= 8192;
  if (blk < 6144 || blk >= 6400) {
    const float* in; short* out; int C, bx, by;
    if (blk < 4096)      { in = wq; out = wq_t; C = 2048; bx = blk & 63; by = blk >> 6; }
    else if (blk < 5120) { int lo = blk - 4096; in = wk; out = wk_t; C = 512; bx = lo & 15; by = lo >> 4; }
    else if (blk < 6144) { int lo = blk - 5120; in = wv; out = wv_t; C = 512; bx = lo & 15; by = lo >> 4; }
    else                 { int lo = blk - 6400; in = wo; out = wo_t; C = 2048; bx = lo & 63; by = lo >> 6; }
    const int c0 = bx * 32, r0 = by * 32;
    const int tx = tid & 31, ty = tid >> 5;
#pragma unroll
    for (int j = 0; j < 32; j += 8)
      t[ty + j][tx] = in[(size_t)(r0 + ty + j) * C + c0 + tx];
    __syncthreads();
#pragma unroll
    for (int j = 0; j < 32; j += 8)
      out[(size_t)(c0 + ty + j) * DIM + r0 + tx] = f2bf(t[tx][ty + j]);
    return;
  }
  {
    int i = (blk - 6144) * 256 + tid;  // [0, 65536) = SEQ*32
    int pos = i >> 5, f = i & 31;
    float inv = powf(10000.0f, -(float)f / 32.0f);
    float th = (float)pos * inv;
    ct[i] = cosf(th);
    st[i] = sinf(th);
  }
}

// standalone wo transpose (fallback when workspace too small for separate wo_t)
__global__ void transpose_bf_kernel(const float* __restrict__ in, short* __restrict__ out,
                                    int R, int C) {
  __shared__ float t[32][33];
  int c0 = blockIdx.x * 32, r0 = blockIdx.y * 32;
  int tx = threadIdx.x, ty = threadIdx.y;  // (32, 8)
#pragma unroll
  for (int j = 0; j < 32; j += 8)
    t[ty + j][tx] = in[(size_t)(r0 + ty + j) * C + c0 + tx];
  __syncthreads();
#pragma unroll
  for (int j = 0; j < 32; j += 8)
    out[(size_t)(c0 + ty + j) * R + r0 + tx] = f2bf(t[tx][ty + j]);
}

// ---------------- pipelined GEMM mainloop (round-4/7 proven config) ----------------
// 128x128 tile, BK=32, 4 waves (2x2), 3 LDS buffers (48 KB), stage t+2 while
// computing t, counted vmcnt(4) per tile, 16x16x32 MFMA.
// Swizzle: 16B-unit ^= (row>>1)&3 -> conflict-free (measured 0).

__device__ __forceinline__ void mfma_tile(const short* __restrict__ as_,
                                          const short* __restrict__ bs_,
                                          int wr, int wc, int lg, int lr,
                                          f32x4 (&acc)[4][4]) {
  short8 af[4], bq[4];
#pragma unroll
  for (int mt = 0; mt < 4; ++mt) {
    int row = wr * 64 + mt * 16 + lr;
    af[mt] = *(const short8*)&as_[row * 32 + ((lg ^ ((row >> 1) & 3)) << 3)];
  }
#pragma unroll
  for (int nt = 0; nt < 4; ++nt) {
    int row = wc * 64 + nt * 16 + lr;
    bq[nt] = *(const short8*)&bs_[row * 32 + ((lg ^ ((row >> 1) & 3)) << 3)];
  }
  __builtin_amdgcn_s_setprio(1);
#pragma unroll
  for (int mt = 0; mt < 4; ++mt)
#pragma unroll
    for (int nt = 0; nt < 4; ++nt)
      acc[mt][nt] = __builtin_amdgcn_mfma_f32_16x16x32_bf16(af[mt], bq[nt], acc[mt][nt], 0, 0, 0);
  __builtin_amdgcn_s_setprio(0);
}

#define STAGE4(SA, SB) do {                                                  \
    GLD16(pA0, (SA) + w * 512);  GLD16(pA1, (SA) + 2048 + w * 512);          \
    GLD16(pB0, (SB) + w * 512);  GLD16(pB1, (SB) + 2048 + w * 512);          \
    pA0 += 32; pA1 += 32; pB0 += 32; pB1 += 32; } while (0)

#define TILE(CA, CB, SA, SB, DOSTAGE, VM) do {                               \
    asm volatile("s_waitcnt vmcnt(" VM ")" ::: "memory");                    \
    __builtin_amdgcn_s_barrier();                                            \
    __builtin_amdgcn_sched_barrier(0);                                       \
    if (DOSTAGE) { STAGE4(SA, SB); }                                         \
    mfma_tile(CA, CB, wr, wc, lg, lr, acc);                                  \
  } while (0)

// As/Bs: 3 buffers of 4096 shorts each (8 KB per buffer per operand)
__device__ __forceinline__ void gemm_mainloop(const short* __restrict__ A,
                                              const short* __restrict__ Bt,
                                              int m0, int n0,
                                              short* As, short* Bs,
                                              f32x4 (&acc)[4][4]) {
  const int tid = threadIdx.x;
  const int w = tid >> 6, l = tid & 63;
  const int lg = l >> 4, lr = l & 15;
  const int wr = w >> 1, wc = w & 1;
  // staging map: chunk c -> row=c>>2, 16B-unit u=c&3; source unit pre-swizzled
  const int c1 = tid + 256;
  const int r0 = tid >> 2, k0 = ((tid & 3) ^ ((r0 >> 1) & 3)) << 3;
  const int r1 = c1 >> 2,  k1 = ((c1 & 3) ^ ((r1 >> 1) & 3)) << 3;
  const short* pA0 = A + (size_t)(m0 + r0) * DIM + k0;
  const short* pA1 = A + (size_t)(m0 + r1) * DIM + k1;
  const short* pB0 = Bt + (size_t)(n0 + r0) * DIM + k0;
  const short* pB1 = Bt + (size_t)(n0 + r1) * DIM + k1;
  short* A0 = As;            short* B0 = Bs;
  short* A1 = As + 4096;     short* B1 = Bs + 4096;
  short* A2 = As + 8192;     short* B2 = Bs + 8192;

  // prologue: stage tiles 0 and 1
  STAGE4(A0, B0);
  STAGE4(A1, B1);

  // 64 K-tiles total: 20x3 main + 4 peeled
  for (int it = 0; it < 20; ++it) {
    TILE(A0, B0, A2, B2, true, "4");
    TILE(A1, B1, A0, B0, true, "4");
    TILE(A2, B2, A1, B1, true, "4");
  }
  TILE(A0, B0, A2, B2, true,  "4");  // t=60, stage t=62
  TILE(A1, B1, A0, B0, true,  "4");  // t=61, stage t=63
  TILE(A2, B2, A0, B0, false, "4");  // t=62
  TILE(A0, B0, A1, B1, false, "0");  // t=63
}

__device__ __forceinline__ int2 xcd_swizzle(int nwg) {
  int id = blockIdx.y * gridDim.x + blockIdx.x;
  int swz = (id & 7) * (nwg >> 3) + (id >> 3);
  return make_int2(swz % gridDim.x, swz / gridDim.x);
}

// ---------------- fused QKV projection ----------------
__global__ void __launch_bounds__(256, 3)
gemm_qkv_kernel(const short* __restrict__ A,
                const short* __restrict__ wqt, const short* __restrict__ wkt,
                const short* __restrict__ wvt,
                short* __restrict__ q_ws, short* __restrict__ k_ws, short* __restrict__ v_ws,
                const float* __restrict__ ct, const float* __restrict__ st) {
  __shared__ __align__(16) short As[12288];
  __shared__ __align__(16) short Bs[12288];
  int2 bxy = xcd_swizzle(24 * 32);
  const int n0g = bxy.x * 128;
  const int m0 = bxy.y * 128;
  int mode, n0;
  const short* Bt;
  short* outp;
  if (n0g < 2048)      { mode = 1; Bt = wqt; n0 = n0g;        outp = q_ws; }
  else if (n0g < 2560) { mode = 2; Bt = wkt; n0 = n0g - 2048; outp = k_ws; }
  else                 { mode = 3; Bt = wvt; n0 = n0g - 2560; outp = v_ws; }

  f32x4 acc[4][4] = {};
  gemm_mainloop(A, Bt, m0, n0, As, Bs, acc);

  const int tid = threadIdx.x;
  const int w = tid >> 6, l = tid & 63;
  const int lg = l >> 4, lr = l & 15;
  const int wr = w >> 1, wc = w & 1;
  const int mrow0 = m0 + wr * 64;
  const int ncol0 = n0 + wc * 64;
#pragma unroll
  for (int mt = 0; mt < 4; ++mt)
#pragma unroll
    for (int nt = 0; nt < 4; ++nt)
#pragma unroll
      for (int i = 0; i < 4; ++i) {
        int m = mrow0 + mt * 16 + lg * 4 + i;
        int n = ncol0 + nt * 16 + lr;
        float v = acc[mt][nt][i];
        int b = m >> 11, s = m & (SEQ - 1);
        int h = n >> 6, d = n & 63;
        if (mode == 3) {
          outp[((size_t)(b * NKV + h) * HD + d) * SEQ + s] = f2bf(v);
        } else {
          float p = __shfl_xor(v, 1);
          float cs = ct[(s << 5) + (d >> 1)];
          float sn = st[(s << 5) + (d >> 1)];
          float r = ((d & 1) == 0) ? (v * cs - p * sn) : (p * sn + v * cs);
          if (mode == 1) {
            r *= QSCALE;  // 1/sqrt(HD) * log2(e): softmax done in exp2 domain
            outp[((size_t)(b * NH + h) * SEQ + s) * HD + d] = f2bf(r);
          } else {
            outp[((size_t)(b * NKV + h) * SEQ + s) * HD + d] = f2bf(r);
          }
        }
      }
}

// ---------------- O projection (f32 out) ----------------
__global__ void __launch_bounds__(256, 3)
gemm_o_kernel(const short* __restrict__ A, const short* __restrict__ Bt,
              float* __restrict__ out) {
  __shared__ __align__(16) short As[12288];
  __shared__ __align__(16) short Bs[12288];
  int2 bxy = xcd_swizzle(16 * 32);
  const int m0 = bxy.y * 128, n0 = bxy.x * 128;
  f32x4 acc[4][4] = {};
  gemm_mainloop(A, Bt, m0, n0, As, Bs, acc);
  const int tid = threadIdx.x;
  const int w = tid >> 6, l = tid & 63;
  const int lg = l >> 4, lr = l & 15;
  const int wr = w >> 1, wc = w & 1;
#pragma unroll
  for (int mt = 0; mt < 4; ++mt)
#pragma unroll
    for (int nt = 0; nt < 4; ++nt)
#pragma unroll
      for (int i = 0; i < 4; ++i) {
        int m = m0 + wr * 64 + mt * 16 + lg * 4 + i;
        int n = n0 + wc * 64 + nt * 16 + lr;
        out[(size_t)m * DIM + n] = acc[mt][nt][i];
      }
}

// ---------------- flash attention (swapped QK^T, GQA, causal, exp2 domain) ----------------
// Q: [b][h][s][d] bf16 (pre-scaled by QSCALE), K: [b][kvh][s][d], V: [b][kvh][d][s]
// O: [b][s][h*HD+d] bf16
// Merged dual-q blocks: block x processes q-tiles A=x and B=31-x over ONE pass
// t=0..31-x, staging each KV tile once (A consumes while t<=x).  Shared-prefix
// tiles do 2x MFMA+softmax per barrier pair; staging volume -26% vs 2-pass.
__global__ void __launch_bounds__(256, 3)
attn_fwd_kernel(const short* __restrict__ Q, const short* __restrict__ K,
                const short* __restrict__ V, short* __restrict__ O) {
  __shared__ __align__(16) short Ks[3][4096];  // [64 keys][64 dims], xor-swizzled
  __shared__ __align__(16) short Vs[3][4096];  // [64 dims][64 keys], xor-swizzled
  const int tid = threadIdx.x;
  const int w = tid >> 6, l = tid & 63;
  const int lg = l >> 4, lr = l & 15;
  const int h = blockIdx.y;
  const int b = blockIdx.z;
  const int kvh = h >> 2;
  const int lh = lg >> 1, sub = (lg & 1) << 2;

  const short* kbase = K + (size_t)(b * NKV + kvh) * SEQ * HD;
  const short* vbase = V + (size_t)(b * NKV + kvh) * HD * SEQ;

  const int c1 = tid + 256;
  const int r0 = tid >> 3, e0 = ((tid & 7) ^ (r0 & 7)) << 3;
  const int r1 = c1 >> 3, e1 = ((c1 & 7) ^ (r1 & 7)) << 3;

  short8 ones;
#pragma unroll
  for (int i = 0; i < 8; ++i) ones[i] = (short)0x3F80;  // bf16 1.0

#define ASTAGE(kvt, KB, VB) do { const int kv_ = (kvt) * 64;                  \
    GLD16(kbase + (size_t)(kv_ + r0) * HD + e0, (KB) + w * 512);              \
    GLD16(kbase + (size_t)(kv_ + r1) * HD + e1, (KB) + 2048 + w * 512);       \
    GLD16(vbase + (size_t)r0 * SEQ + kv_ + e0, (VB) + w * 512);               \
    GLD16(vbase + (size_t)r1 * SEQ + kv_ + e1, (VB) + 2048 + w * 512); } while (0)

  const int xa = (int)blockIdx.x;   // q-tile A
  const int T = 31 - xa;            // q-tile B (= KV extent)
  const int qrowA = xa * 64 + w * 16 + lr;
  const int qrowB = T * 64 + w * 16 + lr;

  const short* qbase = Q + (size_t)(b * NH + h) * SEQ * HD;
  const short* qpA = qbase + (size_t)qrowA * HD;
  const short* qpB = qbase + (size_t)qrowB * HD;
  short8 qfA0 = *(const short8*)(qpA + (lg << 3));
  short8 qfA1 = *(const short8*)(qpA + 32 + (lg << 3));
  short8 qfB0 = *(const short8*)(qpB + (lg << 3));
  short8 qfB1 = *(const short8*)(qpB + 32 + (lg << 3));

  float m_runA = 0.f, m_runB = 0.f;   // running max, log2 domain (defer-max)
  f32x4 oaccA[4] = {}, oaccB[4] = {};
  f32x4 laccA = {}, laccB = {};

  short* kb0 = Ks[0]; short* kb1 = Ks[1]; short* kb2 = Ks[2];
  short* vb0 = Vs[0]; short* vb1 = Vs[1]; short* vb2 = Vs[2];

  ASTAGE(0, kb0, vb0);
  ASTAGE(1, kb1, vb1);   // T >= 16, always valid

  short8 ka[4][2];
  short8 vbf[4][2];
  int kv0 = 0;

  // per-tile softmax+PV for one q-state (sacc/pa registers reused across calls)
  auto process = [&](const short8& qf0, const short8& qf1, float& m_run,
                     f32x4 (&oacc)[4], f32x4& lacc, int qrow, bool diag) {
    f32x4 sacc[4];
    {
      f32x4 seed;
      seed[0] = -m_run; seed[1] = -m_run; seed[2] = -m_run; seed[3] = -m_run;
      __builtin_amdgcn_s_setprio(1);
#pragma unroll
      for (int t4 = 0; t4 < 4; ++t4) {
        f32x4 z = __builtin_amdgcn_mfma_f32_16x16x32_bf16(ka[t4][0], qf0, seed, 0, 0, 0);
        sacc[t4] = __builtin_amdgcn_mfma_f32_16x16x32_bf16(ka[t4][1], qf1, z, 0, 0, 0);
      }
      __builtin_amdgcn_s_setprio(0);
    }

    if (diag) {  // causal mask on the diagonal tile
#pragma unroll
      for (int t4 = 0; t4 < 4; ++t4)
#pragma unroll
        for (int i = 0; i < 4; ++i)
          if (kv0 + t4 * 16 + lg * 4 + i > qrow) sacc[t4][i] = -__builtin_inff();
    }

    // tile max in shifted domain
    float a0 = fmaxf(fmaxf(sacc[0][0], sacc[0][1]), sacc[0][2]);
    float a1 = fmaxf(fmaxf(sacc[0][3], sacc[1][0]), sacc[1][1]);
    float a2 = fmaxf(fmaxf(sacc[1][2], sacc[1][3]), sacc[2][0]);
    float a3 = fmaxf(fmaxf(sacc[2][1], sacc[2][2]), sacc[2][3]);
    float a4 = fmaxf(fmaxf(sacc[3][0], sacc[3][1]), sacc[3][2]);
    float tm = fmaxf(fmaxf(fmaxf(a0, a1), a2), fmaxf(fmaxf(a3, a4), sacc[3][3]));
    tm = fmaxf(tm, __shfl_xor(tm, 16));
    tm = fmaxf(tm, __shfl_xor(tm, 32));

    // defer-max: rescale only when shifted max exceeds THR (P <= 2^12 otherwise)
    if (!__all(tm <= 12.0f)) {
      float d = fmaxf(tm, 0.f);
      float alpha = EXP2(-d);
      float av0 = __shfl(alpha, (lg << 2));
      float av1 = __shfl(alpha, (lg << 2) | 1);
      float av2 = __shfl(alpha, (lg << 2) | 2);
      float av3 = __shfl(alpha, (lg << 2) | 3);
#pragma unroll
      for (int nt = 0; nt < 4; ++nt) {
        oacc[nt][0] *= av0; oacc[nt][1] *= av1;
        oacc[nt][2] *= av2; oacc[nt][3] *= av3;
      }
      lacc[0] *= av0; lacc[1] *= av1; lacc[2] *= av2; lacc[3] *= av3;
      m_run += d;
#pragma unroll
      for (int t4 = 0; t4 < 4; ++t4)
#pragma unroll
        for (int i = 0; i < 4; ++i) sacc[t4][i] -= d;
    }

    // P = exp2(S') packed straight to bf16 fragments (k-bijection feeds PV A)
    union { short8 s8; uint32_t u[4]; } pa0, pa1;
    pa0.u[0] = cvtpk_bf16(EXP2(sacc[0][0]), EXP2(sacc[0][1]));
    pa0.u[1] = cvtpk_bf16(EXP2(sacc[0][2]), EXP2(sacc[0][3]));
    pa0.u[2] = cvtpk_bf16(EXP2(sacc[1][0]), EXP2(sacc[1][1]));
    pa0.u[3] = cvtpk_bf16(EXP2(sacc[1][2]), EXP2(sacc[1][3]));
    pa1.u[0] = cvtpk_bf16(EXP2(sacc[2][0]), EXP2(sacc[2][1]));
    pa1.u[1] = cvtpk_bf16(EXP2(sacc[2][2]), EXP2(sacc[2][3]));
    pa1.u[2] = cvtpk_bf16(EXP2(sacc[3][0]), EXP2(sacc[3][1]));
    pa1.u[3] = cvtpk_bf16(EXP2(sacc[3][2]), EXP2(sacc[3][3]));

    // O += P * V; l += P * ones  (row-sum via MFMA)
    __builtin_amdgcn_s_setprio(1);
#pragma unroll
    for (int nt = 0; nt < 4; ++nt) {
      oacc[nt] = __builtin_amdgcn_mfma_f32_16x16x32_bf16(pa0.s8, vbf[nt][0], oacc[nt], 0, 0, 0);
      oacc[nt] = __builtin_amdgcn_mfma_f32_16x16x32_bf16(pa1.s8, vbf[nt][1], oacc[nt], 0, 0, 0);
    }
    lacc = __builtin_amdgcn_mfma_f32_16x16x32_bf16(pa0.s8, ones, lacc, 0, 0, 0);
    lacc = __builtin_amdgcn_mfma_f32_16x16x32_bf16(pa1.s8, ones, lacc, 0, 0, 0);
    __builtin_amdgcn_s_setprio(0);
  };

  for (int t = 0; t <= T; ++t) {
    if (t < T) asm volatile("s_waitcnt vmcnt(4)" ::: "memory");
    else       asm volatile("s_waitcnt vmcnt(0)" ::: "memory");
    __builtin_amdgcn_s_barrier();
    __builtin_amdgcn_sched_barrier(0);
    if (t + 2 <= T) ASTAGE(t + 2, kb2, vb2);

    const short* ks = kb0;
    const short* vs = vb0;
    kv0 = t * 64;

    // hoist K fragments (8 x b128) and V fragments (16 x b64) — shared by A and B
#pragma unroll
    for (int t4 = 0; t4 < 4; ++t4) {
      int row = t4 * 16 + lr, rx = row & 7;
      ka[t4][0] = *(const short8*)&ks[row * 64 + ((lg ^ rx) << 3)];
      ka[t4][1] = *(const short8*)&ks[row * 64 + (((4 + lg) ^ rx) << 3)];
    }
#pragma unroll
    for (int nt = 0; nt < 4; ++nt) {
      int row = nt * 16 + lr, rx = row & 7;
#pragma unroll
      for (int ks_ = 0; ks_ < 2; ++ks_) {
        union { short8 s8; short4v hh[2]; } u;
        u.hh[0] = *(const short4v*)&vs[row * 64 + (((4 * ks_ + lh) ^ rx) << 3) + sub];
        u.hh[1] = *(const short4v*)&vs[row * 64 + (((4 * ks_ + 2 + lh) ^ rx) << 3) + sub];
        vbf[nt][ks_] = u.s8;
      }
    }

    if (t <= xa) process(qfA0, qfA1, m_runA, oaccA, laccA, qrowA, t == xa);
    process(qfB0, qfB1, m_runB, oaccB, laccB, qrowB, t == T);

    short* tk = kb0; kb0 = kb1; kb1 = kb2; kb2 = tk;
    short* tv = vb0; vb0 = vb1; vb1 = vb2; vb2 = tv;
  }

  // epilogue: normalize and store both q-tiles (l already in oacc row layout)
  auto epilogue = [&](f32x4 (&oacc)[4], f32x4& lacc, int q0) {
    float linv0 = 1.f / lacc[0], linv1 = 1.f / lacc[1];
    float linv2 = 1.f / lacc[2], linv3 = 1.f / lacc[3];
#pragma unroll
    for (int nt = 0; nt < 4; ++nt) {
      int d = nt * 16 + lr;
      int qb = q0 + w * 16 + lg * 4;
      O[(size_t)(b * SEQ + qb + 0) * DIM + h * HD + d] = f2bf(oacc[nt][0] * linv0);
      O[(size_t)(b * SEQ + qb + 1) * DIM + h * HD + d] = f2bf(oacc[nt][1] * linv1);
      O[(size_t)(b * SEQ + qb + 2) * DIM + h * HD + d] = f2bf(oacc[nt][2] * linv2);
      O[(size_t)(b * SEQ + qb + 3) * DIM + h * HD + d] = f2bf(oacc[nt][3] * linv3);
    }
  };
  epilogue(oaccA, laccA, xa * 64);
  epilogue(oaccB, laccB, T * 64);
#undef ASTAGE
}

// ---------------- launch ----------------

extern "C" void kernel_launch(void* const* d_in, const int* in_sizes, int n_in,
                              void* d_out, int out_size, void* d_ws, size_t ws_size,
                              hipStream_t stream) {
  const float* x  = (const float*)d_in[0];
  const float* wq = (const float*)d_in[1];
  const float* wk = (const float*)d_in[2];
  const float* wv = (const float*)d_in[3];
  const float* wo = (const float*)d_in[4];
  float* out = (float*)d_out;
  char* ws = (char*)d_ws;

  short* x_bf  = (short*)(ws + 0);          // 16 MB  [4096][2048]
  short* attn  = (short*)(ws + 0);          // alias of x_bf (dead after QKV GEMM)
  short* q_ws  = (short*)(ws + 16777216);   // 16 MB  [b][h][s][d]
  short* k_ws  = (short*)(ws + 33554432);   // 4 MB   [b][kvh][s][d]
  short* v_ws  = (short*)(ws + 37748736);   // 4 MB   [b][kvh][d][s]
  short* wq_t  = (short*)(ws + 41943040);   // 8 MB   [N][K]
  short* wk_t  = (short*)(ws + 50331648);   // 2 MB
  short* wv_t  = (short*)(ws + 52428800);   // 2 MB
  float* ct    = (float*)(ws + 54525952);   // 256 KB
  float* st    = (float*)(ws + 54788096);   // 256 KB
  // fast path: dedicated wo_t (8 MB) so the wo transpose fuses into prep
  const int sep_wo = (ws_size >= (size_t)63438848);
  short* wo_t  = sep_wo ? (short*)(ws + 55050240) : wq_t;  // alias wq_t in fallback
  (void)in_sizes; (void)n_in; (void)out_size;

  // fused prep: cvt_x + wq/wk/wv (+wo when sep) transposes + rope table
  prep_kernel<<<sep_wo ? 18688 : 14592, 256, 0, stream>>>(
      x, wq, wk, wv, wo, x_bf, wq_t, wk_t, wv_t, wo_t, ct, st);

  gemm_qkv_kernel<<<dim3(24, 32), 256, 0, stream>>>(x_bf, wq_t, wk_t, wv_t,
                                                    q_ws, k_ws, v_ws, ct, st);

  if (!sep_wo)  // fallback: wo transpose after qkv (wo_t aliases wq_t)
    transpose_bf_kernel<<<dim3(64, 64), dim3(32, 8), 0, stream>>>(wo, wo_t, DIM, 2048);

  attn_fwd_kernel<<<dim3(16, 32, 2), 256, 0, stream>>>(q_ws, k_ws, v_ws, attn);

  gemm_o_kernel<<<dim3(16, 32), 256, 0, stream>>>(attn, wo_t, out);
}

// Round 12
// 211.791 us; speedup vs baseline: 1.5241x; 1.5241x over previous
//
#include <hip/hip_runtime.h>
#include <stdint.h>

#define DIM   2048
#define NH    32
#define NKV   8
#define HD    64
#define BATCH 2
#define SEQ   2048

typedef __attribute__((ext_vector_type(8))) short  short8;
typedef __attribute__((ext_vector_type(4))) short  short4v;
typedef __attribute__((ext_vector_type(4))) float  f32x4;

#if __has_builtin(__builtin_amdgcn_exp2f)
#define EXP2(x) __builtin_amdgcn_exp2f(x)
#else
#define EXP2(x) exp2f(x)
#endif

static __device__ __forceinline__ short f2bf(float f) {
  union { float f; uint32_t u; } v; v.f = f;
  uint32_t r = v.u + 0x7FFFu + ((v.u >> 16) & 1u);
  return (short)(r >> 16);
}

static __device__ __forceinline__ uint32_t cvtpk_bf16(float lo, float hi) {
  uint32_t r;
  asm("v_cvt_pk_bf16_f32 %0, %1, %2" : "=v"(r) : "v"(lo), "v"(hi));
  return r;
}

#define GLD16(gp, lp) __builtin_amdgcn_global_load_lds(                      \
    (__attribute__((address_space(1))) void*)(void*)(gp),                    \
    (__attribute__((address_space(3))) void*)(lp), 16, 0, 0)

// log2(e) * (1/sqrt(HD))  folded into Q at projection time
#define QSCALE 0.1803368801111244f

// ---------------- fused prep: cvt_x + w transposes + rope table ----------------
__global__ void __launch_bounds__(256)
prep_kernel(const float* __restrict__ x, const float* __restrict__ wq,
            const float* __restrict__ wk, const float* __restrict__ wv,
            const float* __restrict__ wo,
            short* __restrict__ x_bf, short* __restrict__ wq_t,
            short* __restrict__ wk_t, short* __restrict__ wv_t,
            short* __restrict__ wo_t,
            float* __restrict__ ct, float* __restrict__ st) {
  __shared__ float t[32][33];
  int blk = blockIdx.x;
  const int tid = threadIdx.x;
  if (blk < 8192) {
    int i = blk * 256 + tid;
    f32x4 v = *reinterpret_cast<const f32x4*>(x + (size_t)i * 4);
    short4v o;
    o.x = f2bf(v.x); o.y = f2bf(v.y); o.z = f2bf(v.z); o.w = f2bf(v.w);
    *reinterpret_cast<short4v*>(x_bf + (size_t)i * 4) = o;
    return;
  }
  blk -= 8192;
  if (blk < 6144 || blk >= 6400) {
    const float* in; short* out; int C, bx, by;
    if (blk < 4096)      { in = wq; out = wq_t; C = 2048; bx = blk & 63; by = blk >> 6; }
    else if (blk < 5120) { int lo = blk - 4096; in = wk; out = wk_t; C = 512; bx = lo & 15; by = lo >> 4; }
    else if (blk < 6144) { int lo = blk - 5120; in = wv; out = wv_t; C = 512; bx = lo & 15; by = lo >> 4; }
    else                 { int lo = blk - 6400; in = wo; out = wo_t; C = 2048; bx = lo & 63; by = lo >> 6; }
    const int c0 = bx * 32, r0 = by * 32;
    const int tx = tid & 31, ty = tid >> 5;
#pragma unroll
    for (int j = 0; j < 32; j += 8)
      t[ty + j][tx] = in[(size_t)(r0 + ty + j) * C + c0 + tx];
    __syncthreads();
#pragma unroll
    for (int j = 0; j < 32; j += 8)
      out[(size_t)(c0 + ty + j) * DIM + r0 + tx] = f2bf(t[tx][ty + j]);
    return;
  }
  {
    int i = (blk - 6144) * 256 + tid;  // [0, 65536) = SEQ*32
    int pos = i >> 5, f = i & 31;
    float inv = powf(10000.0f, -(float)f / 32.0f);
    float th = (float)pos * inv;
    ct[i] = cosf(th);
    st[i] = sinf(th);
  }
}

// standalone wo transpose (fallback when workspace too small for separate wo_t)
__global__ void transpose_bf_kernel(const float* __restrict__ in, short* __restrict__ out,
                                    int R, int C) {
  __shared__ float t[32][33];
  int c0 = blockIdx.x * 32, r0 = blockIdx.y * 32;
  int tx = threadIdx.x, ty = threadIdx.y;  // (32, 8)
#pragma unroll
  for (int j = 0; j < 32; j += 8)
    t[ty + j][tx] = in[(size_t)(r0 + ty + j) * C + c0 + tx];
  __syncthreads();
#pragma unroll
  for (int j = 0; j < 32; j += 8)
    out[(size_t)(c0 + ty + j) * R + r0 + tx] = f2bf(t[tx][ty + j]);
}

// ---------------- pipelined GEMM mainloop (round-4/7 proven config) ----------------
// 128x128 tile, BK=32, 4 waves (2x2), 3 LDS buffers (48 KB), stage t+2 while
// computing t, counted vmcnt(4) per tile, 16x16x32 MFMA.
// Swizzle: 16B-unit ^= (row>>1)&3 -> conflict-free (measured 0).

__device__ __forceinline__ void mfma_tile(const short* __restrict__ as_,
                                          const short* __restrict__ bs_,
                                          int wr, int wc, int lg, int lr,
                                          f32x4 (&acc)[4][4]) {
  short8 af[4], bq[4];
#pragma unroll
  for (int mt = 0; mt < 4; ++mt) {
    int row = wr * 64 + mt * 16 + lr;
    af[mt] = *(const short8*)&as_[row * 32 + ((lg ^ ((row >> 1) & 3)) << 3)];
  }
#pragma unroll
  for (int nt = 0; nt < 4; ++nt) {
    int row = wc * 64 + nt * 16 + lr;
    bq[nt] = *(const short8*)&bs_[row * 32 + ((lg ^ ((row >> 1) & 3)) << 3)];
  }
  __builtin_amdgcn_s_setprio(1);
#pragma unroll
  for (int mt = 0; mt < 4; ++mt)
#pragma unroll
    for (int nt = 0; nt < 4; ++nt)
      acc[mt][nt] = __builtin_amdgcn_mfma_f32_16x16x32_bf16(af[mt], bq[nt], acc[mt][nt], 0, 0, 0);
  __builtin_amdgcn_s_setprio(0);
}

#define STAGE4(SA, SB) do {                                                  \
    GLD16(pA0, (SA) + w * 512);  GLD16(pA1, (SA) + 2048 + w * 512);          \
    GLD16(pB0, (SB) + w * 512);  GLD16(pB1, (SB) + 2048 + w * 512);          \
    pA0 += 32; pA1 += 32; pB0 += 32; pB1 += 32; } while (0)

#define TILE(CA, CB, SA, SB, DOSTAGE, VM) do {                               \
    asm volatile("s_waitcnt vmcnt(" VM ")" ::: "memory");                    \
    __builtin_amdgcn_s_barrier();                                            \
    __builtin_amdgcn_sched_barrier(0);                                       \
    if (DOSTAGE) { STAGE4(SA, SB); }                                         \
    mfma_tile(CA, CB, wr, wc, lg, lr, acc);                                  \
  } while (0)

// As/Bs: 3 buffers of 4096 shorts each (8 KB per buffer per operand)
__device__ __forceinline__ void gemm_mainloop(const short* __restrict__ A,
                                              const short* __restrict__ Bt,
                                              int m0, int n0,
                                              short* As, short* Bs,
                                              f32x4 (&acc)[4][4]) {
  const int tid = threadIdx.x;
  const int w = tid >> 6, l = tid & 63;
  const int lg = l >> 4, lr = l & 15;
  const int wr = w >> 1, wc = w & 1;
  // staging map: chunk c -> row=c>>2, 16B-unit u=c&3; source unit pre-swizzled
  const int c1 = tid + 256;
  const int r0 = tid >> 2, k0 = ((tid & 3) ^ ((r0 >> 1) & 3)) << 3;
  const int r1 = c1 >> 2,  k1 = ((c1 & 3) ^ ((r1 >> 1) & 3)) << 3;
  const short* pA0 = A + (size_t)(m0 + r0) * DIM + k0;
  const short* pA1 = A + (size_t)(m0 + r1) * DIM + k1;
  const short* pB0 = Bt + (size_t)(n0 + r0) * DIM + k0;
  const short* pB1 = Bt + (size_t)(n0 + r1) * DIM + k1;
  short* A0 = As;            short* B0 = Bs;
  short* A1 = As + 4096;     short* B1 = Bs + 4096;
  short* A2 = As + 8192;     short* B2 = Bs + 8192;

  // prologue: stage tiles 0 and 1
  STAGE4(A0, B0);
  STAGE4(A1, B1);

  // 64 K-tiles total: 20x3 main + 4 peeled
  for (int it = 0; it < 20; ++it) {
    TILE(A0, B0, A2, B2, true, "4");
    TILE(A1, B1, A0, B0, true, "4");
    TILE(A2, B2, A1, B1, true, "4");
  }
  TILE(A0, B0, A2, B2, true,  "4");  // t=60, stage t=62
  TILE(A1, B1, A0, B0, true,  "4");  // t=61, stage t=63
  TILE(A2, B2, A0, B0, false, "4");  // t=62
  TILE(A0, B0, A1, B1, false, "0");  // t=63
}

__device__ __forceinline__ int2 xcd_swizzle(int nwg) {
  int id = blockIdx.y * gridDim.x + blockIdx.x;
  int swz = (id & 7) * (nwg >> 3) + (id >> 3);
  return make_int2(swz % gridDim.x, swz / gridDim.x);
}

// ---------------- fused QKV projection ----------------
__global__ void __launch_bounds__(256, 3)
gemm_qkv_kernel(const short* __restrict__ A,
                const short* __restrict__ wqt, const short* __restrict__ wkt,
                const short* __restrict__ wvt,
                short* __restrict__ q_ws, short* __restrict__ k_ws, short* __restrict__ v_ws,
                const float* __restrict__ ct, const float* __restrict__ st) {
  __shared__ __align__(16) short As[12288];
  __shared__ __align__(16) short Bs[12288];
  int2 bxy = xcd_swizzle(24 * 32);
  const int n0g = bxy.x * 128;
  const int m0 = bxy.y * 128;
  int mode, n0;
  const short* Bt;
  short* outp;
  if (n0g < 2048)      { mode = 1; Bt = wqt; n0 = n0g;        outp = q_ws; }
  else if (n0g < 2560) { mode = 2; Bt = wkt; n0 = n0g - 2048; outp = k_ws; }
  else                 { mode = 3; Bt = wvt; n0 = n0g - 2560; outp = v_ws; }

  f32x4 acc[4][4] = {};
  gemm_mainloop(A, Bt, m0, n0, As, Bs, acc);

  const int tid = threadIdx.x;
  const int w = tid >> 6, l = tid & 63;
  const int lg = l >> 4, lr = l & 15;
  const int wr = w >> 1, wc = w & 1;
  const int mrow0 = m0 + wr * 64;
  const int ncol0 = n0 + wc * 64;
#pragma unroll
  for (int mt = 0; mt < 4; ++mt)
#pragma unroll
    for (int nt = 0; nt < 4; ++nt)
#pragma unroll
      for (int i = 0; i < 4; ++i) {
        int m = mrow0 + mt * 16 + lg * 4 + i;
        int n = ncol0 + nt * 16 + lr;
        float v = acc[mt][nt][i];
        int b = m >> 11, s = m & (SEQ - 1);
        int h = n >> 6, d = n & 63;
        if (mode == 3) {
          outp[((size_t)(b * NKV + h) * HD + d) * SEQ + s] = f2bf(v);
        } else {
          float p = __shfl_xor(v, 1);
          float cs = ct[(s << 5) + (d >> 1)];
          float sn = st[(s << 5) + (d >> 1)];
          float r = ((d & 1) == 0) ? (v * cs - p * sn) : (p * sn + v * cs);
          if (mode == 1) {
            r *= QSCALE;  // 1/sqrt(HD) * log2(e): softmax done in exp2 domain
            outp[((size_t)(b * NH + h) * SEQ + s) * HD + d] = f2bf(r);
          } else {
            outp[((size_t)(b * NKV + h) * SEQ + s) * HD + d] = f2bf(r);
          }
        }
      }
}

// ---------------- O projection (f32 out) ----------------
__global__ void __launch_bounds__(256, 3)
gemm_o_kernel(const short* __restrict__ A, const short* __restrict__ Bt,
              float* __restrict__ out) {
  __shared__ __align__(16) short As[12288];
  __shared__ __align__(16) short Bs[12288];
  int2 bxy = xcd_swizzle(16 * 32);
  const int m0 = bxy.y * 128, n0 = bxy.x * 128;
  f32x4 acc[4][4] = {};
  gemm_mainloop(A, Bt, m0, n0, As, Bs, acc);
  const int tid = threadIdx.x;
  const int w = tid >> 6, l = tid & 63;
  const int lg = l >> 4, lr = l & 15;
  const int wr = w >> 1, wc = w & 1;
#pragma unroll
  for (int mt = 0; mt < 4; ++mt)
#pragma unroll
    for (int nt = 0; nt < 4; ++nt)
#pragma unroll
      for (int i = 0; i < 4; ++i) {
        int m = m0 + wr * 64 + mt * 16 + lg * 4 + i;
        int n = n0 + wc * 64 + nt * 16 + lr;
        out[(size_t)m * DIM + n] = acc[mt][nt][i];
      }
}

// ---------------- flash attention (swapped QK^T, GQA, causal, exp2 domain) ----------------
// Q: [b][h][s][d] bf16 (pre-scaled by QSCALE), K: [b][kvh][s][d], V: [b][kvh][d][s]
// O: [b][s][h*HD+d] bf16
// 1024 blocks (grid 16x32x2); each processes q-tiles {x, 31-x} = 33 KV tiles.
// 3 blocks/CU co-resident with scheduler backfill (measured best config).
__global__ void __launch_bounds__(256, 3)
attn_fwd_kernel(const short* __restrict__ Q, const short* __restrict__ K,
                const short* __restrict__ V, short* __restrict__ O) {
  __shared__ __align__(16) short Ks[3][4096];  // [64 keys][64 dims], xor-swizzled
  __shared__ __align__(16) short Vs[3][4096];  // [64 dims][64 keys], xor-swizzled
  const int tid = threadIdx.x;
  const int w = tid >> 6, l = tid & 63;
  const int lg = l >> 4, lr = l & 15;
  const int h = blockIdx.y;
  const int b = blockIdx.z;
  const int kvh = h >> 2;
  const int lh = lg >> 1, sub = (lg & 1) << 2;

  const short* kbase = K + (size_t)(b * NKV + kvh) * SEQ * HD;
  const short* vbase = V + (size_t)(b * NKV + kvh) * HD * SEQ;

  const int c1 = tid + 256;
  const int r0 = tid >> 3, e0 = ((tid & 7) ^ (r0 & 7)) << 3;
  const int r1 = c1 >> 3, e1 = ((c1 & 7) ^ (r1 & 7)) << 3;

  short8 ones;
#pragma unroll
  for (int i = 0; i < 8; ++i) ones[i] = (short)0x3F80;  // bf16 1.0

#define ASTAGE(kvt, KB, VB) do { const int kv_ = (kvt) * 64;                  \
    GLD16(kbase + (size_t)(kv_ + r0) * HD + e0, (KB) + w * 512);              \
    GLD16(kbase + (size_t)(kv_ + r1) * HD + e1, (KB) + 2048 + w * 512);       \
    GLD16(vbase + (size_t)r0 * SEQ + kv_ + e0, (VB) + w * 512);               \
    GLD16(vbase + (size_t)r1 * SEQ + kv_ + e1, (VB) + 2048 + w * 512); } while (0)

  for (int qi = 0; qi < 2; ++qi) {
    const int qblk = (qi == 0) ? (int)blockIdx.x : (31 - (int)blockIdx.x);
    const int q0 = qblk * 64;
    const int qrow = q0 + w * 16 + lr;  // this lane's q column (swapped layout)

    const short* qptr = Q + ((size_t)(b * NH + h) * SEQ + qrow) * HD;
    short8 qf0 = *(const short8*)(qptr + (lg << 3));
    short8 qf1 = *(const short8*)(qptr + 32 + (lg << 3));

    float m_run = 0.f;       // running max in log2 domain (defer-max; 0-seed is safe)
    f32x4 oacc[4] = {};
    f32x4 lacc = {};         // row-sums, same row layout as oacc

    short* kb0 = Ks[0]; short* kb1 = Ks[1]; short* kb2 = Ks[2];
    short* vb0 = Vs[0]; short* vb1 = Vs[1]; short* vb2 = Vs[2];

    ASTAGE(0, kb0, vb0);
    if (qblk >= 1) ASTAGE(1, kb1, vb1);

    for (int t = 0; t <= qblk; ++t) {
      if (t < qblk) asm volatile("s_waitcnt vmcnt(4)" ::: "memory");
      else          asm volatile("s_waitcnt vmcnt(0)" ::: "memory");
      __builtin_amdgcn_s_barrier();
      __builtin_amdgcn_sched_barrier(0);
      if (t + 2 <= qblk) ASTAGE(t + 2, kb2, vb2);

      const short* ks = kb0;
      const short* vs = vb0;
      const int kv0 = t * 64;

      // hoist all K fragments (8 x b128) and V fragments (16 x b64)
      short8 ka[4][2];
#pragma unroll
      for (int t4 = 0; t4 < 4; ++t4) {
        int row = t4 * 16 + lr, rx = row & 7;
        ka[t4][0] = *(const short8*)&ks[row * 64 + ((lg ^ rx) << 3)];
        ka[t4][1] = *(const short8*)&ks[row * 64 + (((4 + lg) ^ rx) << 3)];
      }
      short8 vbf[4][2];
#pragma unroll
      for (int nt = 0; nt < 4; ++nt) {
        int row = nt * 16 + lr, rx = row & 7;
#pragma unroll
        for (int ks_ = 0; ks_ < 2; ++ks_) {
          union { short8 s8; short4v hh[2]; } u;
          u.hh[0] = *(const short4v*)&vs[row * 64 + (((4 * ks_ + lh) ^ rx) << 3) + sub];
          u.hh[1] = *(const short4v*)&vs[row * 64 + (((4 * ks_ + 2 + lh) ^ rx) << 3) + sub];
          vbf[nt][ks_] = u.s8;
        }
      }

      // S' = K*Q - m_run  (C seeded with -m_run; col=q matches lane layout)
      f32x4 sacc[4];
      {
        f32x4 seed;
        seed[0] = -m_run; seed[1] = -m_run; seed[2] = -m_run; seed[3] = -m_run;
        __builtin_amdgcn_s_setprio(1);
#pragma unroll
        for (int t4 = 0; t4 < 4; ++t4) {
          f32x4 z = __builtin_amdgcn_mfma_f32_16x16x32_bf16(ka[t4][0], qf0, seed, 0, 0, 0);
          sacc[t4] = __builtin_amdgcn_mfma_f32_16x16x32_bf16(ka[t4][1], qf1, z, 0, 0, 0);
        }
        __builtin_amdgcn_s_setprio(0);
      }

      if (t == qblk) {  // diagonal tile: causal mask
#pragma unroll
        for (int t4 = 0; t4 < 4; ++t4)
#pragma unroll
          for (int i = 0; i < 4; ++i)
            if (kv0 + t4 * 16 + lg * 4 + i > qrow) sacc[t4][i] = -__builtin_inff();
      }

      // tile max in shifted domain (max3-friendly triplet tree)
      float a0 = fmaxf(fmaxf(sacc[0][0], sacc[0][1]), sacc[0][2]);
      float a1 = fmaxf(fmaxf(sacc[0][3], sacc[1][0]), sacc[1][1]);
      float a2 = fmaxf(fmaxf(sacc[1][2], sacc[1][3]), sacc[2][0]);
      float a3 = fmaxf(fmaxf(sacc[2][1], sacc[2][2]), sacc[2][3]);
      float a4 = fmaxf(fmaxf(sacc[3][0], sacc[3][1]), sacc[3][2]);
      float tm = fmaxf(fmaxf(fmaxf(a0, a1), a2), fmaxf(fmaxf(a3, a4), sacc[3][3]));
      tm = fmaxf(tm, __shfl_xor(tm, 16));
      tm = fmaxf(tm, __shfl_xor(tm, 32));

      // defer-max: rescale only when shifted max exceeds THR (P <= 2^12 otherwise)
      if (!__all(tm <= 12.0f)) {
        float d = fmaxf(tm, 0.f);
        float alpha = EXP2(-d);
        float av0 = __shfl(alpha, (lg << 2));
        float av1 = __shfl(alpha, (lg << 2) | 1);
        float av2 = __shfl(alpha, (lg << 2) | 2);
        float av3 = __shfl(alpha, (lg << 2) | 3);
#pragma unroll
        for (int nt = 0; nt < 4; ++nt) {
          oacc[nt][0] *= av0; oacc[nt][1] *= av1;
          oacc[nt][2] *= av2; oacc[nt][3] *= av3;
        }
        lacc[0] *= av0; lacc[1] *= av1; lacc[2] *= av2; lacc[3] *= av3;
        m_run += d;
#pragma unroll
        for (int t4 = 0; t4 < 4; ++t4)
#pragma unroll
          for (int i = 0; i < 4; ++i) sacc[t4][i] -= d;
      }

      // P = exp2(S') packed straight to bf16 fragments (k-bijection feeds PV A)
      union { short8 s8; uint32_t u[4]; } pa0, pa1;
      pa0.u[0] = cvtpk_bf16(EXP2(sacc[0][0]), EXP2(sacc[0][1]));
      pa0.u[1] = cvtpk_bf16(EXP2(sacc[0][2]), EXP2(sacc[0][3]));
      pa0.u[2] = cvtpk_bf16(EXP2(sacc[1][0]), EXP2(sacc[1][1]));
      pa0.u[3] = cvtpk_bf16(EXP2(sacc[1][2]), EXP2(sacc[1][3]));
      pa1.u[0] = cvtpk_bf16(EXP2(sacc[2][0]), EXP2(sacc[2][1]));
      pa1.u[1] = cvtpk_bf16(EXP2(sacc[2][2]), EXP2(sacc[2][3]));
      pa1.u[2] = cvtpk_bf16(EXP2(sacc[3][0]), EXP2(sacc[3][1]));
      pa1.u[3] = cvtpk_bf16(EXP2(sacc[3][2]), EXP2(sacc[3][3]));

      // O += P * V; l += P * ones  (row-sum via MFMA, replaces lsum adds + shfls)
      __builtin_amdgcn_s_setprio(1);
#pragma unroll
      for (int nt = 0; nt < 4; ++nt) {
        oacc[nt] = __builtin_amdgcn_mfma_f32_16x16x32_bf16(pa0.s8, vbf[nt][0], oacc[nt], 0, 0, 0);
        oacc[nt] = __builtin_amdgcn_mfma_f32_16x16x32_bf16(pa1.s8, vbf[nt][1], oacc[nt], 0, 0, 0);
      }
      lacc = __builtin_amdgcn_mfma_f32_16x16x32_bf16(pa0.s8, ones, lacc, 0, 0, 0);
      lacc = __builtin_amdgcn_mfma_f32_16x16x32_bf16(pa1.s8, ones, lacc, 0, 0, 0);
      __builtin_amdgcn_s_setprio(0);

      short* tk = kb0; kb0 = kb1; kb1 = kb2; kb2 = tk;
      short* tv = vb0; vb0 = vb1; vb1 = vb2; vb2 = tv;
    }

    // epilogue: normalize and store (l already in oacc row layout, no shfl)
    float linv0 = 1.f / lacc[0], linv1 = 1.f / lacc[1];
    float linv2 = 1.f / lacc[2], linv3 = 1.f / lacc[3];
#pragma unroll
    for (int nt = 0; nt < 4; ++nt) {
      int d = nt * 16 + lr;
      int qb = q0 + w * 16 + lg * 4;
      O[(size_t)(b * SEQ + qb + 0) * DIM + h * HD + d] = f2bf(oacc[nt][0] * linv0);
      O[(size_t)(b * SEQ + qb + 1) * DIM + h * HD + d] = f2bf(oacc[nt][1] * linv1);
      O[(size_t)(b * SEQ + qb + 2) * DIM + h * HD + d] = f2bf(oacc[nt][2] * linv2);
      O[(size_t)(b * SEQ + qb + 3) * DIM + h * HD + d] = f2bf(oacc[nt][3] * linv3);
    }
    __syncthreads();  // protect LDS buffers before next q-tile's prologue staging
  }
#undef ASTAGE
}

// ---------------- launch ----------------

extern "C" void kernel_launch(void* const* d_in, const int* in_sizes, int n_in,
                              void* d_out, int out_size, void* d_ws, size_t ws_size,
                              hipStream_t stream) {
  const float* x  = (const float*)d_in[0];
  const float* wq = (const float*)d_in[1];
  const float* wk = (const float*)d_in[2];
  const float* wv = (const float*)d_in[3];
  const float* wo = (const float*)d_in[4];
  float* out = (float*)d_out;
  char* ws = (char*)d_ws;

  short* x_bf  = (short*)(ws + 0);          // 16 MB  [4096][2048]
  short* attn  = (short*)(ws + 0);          // alias of x_bf (dead after QKV GEMM)
  short* q_ws  = (short*)(ws + 16777216);   // 16 MB  [b][h][s][d]
  short* k_ws  = (short*)(ws + 33554432);   // 4 MB   [b][kvh][s][d]
  short* v_ws  = (short*)(ws + 37748736);   // 4 MB   [b][kvh][d][s]
  short* wq_t  = (short*)(ws + 41943040);   // 8 MB   [N][K]
  short* wk_t  = (short*)(ws + 50331648);   // 2 MB
  short* wv_t  = (short*)(ws + 52428800);   // 2 MB
  float* ct    = (float*)(ws + 54525952);   // 256 KB
  float* st    = (float*)(ws + 54788096);   // 256 KB
  // fast path: dedicated wo_t (8 MB) so the wo transpose fuses into prep
  const int sep_wo = (ws_size >= (size_t)63438848);
  short* wo_t  = sep_wo ? (short*)(ws + 55050240) : wq_t;  // alias wq_t in fallback
  (void)in_sizes; (void)n_in; (void)out_size;

  // fused prep: cvt_x + wq/wk/wv (+wo when sep) transposes + rope table
  prep_kernel<<<sep_wo ? 18688 : 14592, 256, 0, stream>>>(
      x, wq, wk, wv, wo, x_bf, wq_t, wk_t, wv_t, wo_t, ct, st);

  gemm_qkv_kernel<<<dim3(24, 32), 256, 0, stream>>>(x_bf, wq_t, wk_t, wv_t,
                                                    q_ws, k_ws, v_ws, ct, st);

  if (!sep_wo)  // fallback: wo transpose after qkv (wo_t aliases wq_t)
    transpose_bf_kernel<<<dim3(64, 64), dim3(32, 8), 0, stream>>>(wo, wo_t, DIM, 2048);

  attn_fwd_kernel<<<dim3(16, 32, 2), 256, 0, stream>>>(q_ws, k_ws, v_ws, attn);

  gemm_o_kernel<<<dim3(16, 32), 256, 0, stream>>>(attn, wo_t, out);
}

// Round 13
// 211.202 us; speedup vs baseline: 1.5283x; 1.0028x over previous
//
#include <hip/hip_runtime.h>
#include <stdint.h>

#define DIM   2048
#define NH    32
#define NKV   8
#define HD    64
#define BATCH 2
#define SEQ   2048

typedef __attribute__((ext_vector_type(8))) short  short8;
typedef __attribute__((ext_vector_type(4))) short  short4v;
typedef __attribute__((ext_vector_type(4))) float  f32x4;

#if __has_builtin(__builtin_amdgcn_exp2f)
#define EXP2(x) __builtin_amdgcn_exp2f(x)
#else
#define EXP2(x) exp2f(x)
#endif

static __device__ __forceinline__ short f2bf(float f) {
  union { float f; uint32_t u; } v; v.f = f;
  uint32_t r = v.u + 0x7FFFu + ((v.u >> 16) & 1u);
  return (short)(r >> 16);
}

static __device__ __forceinline__ uint32_t cvtpk_bf16(float lo, float hi) {
  uint32_t r;
  asm("v_cvt_pk_bf16_f32 %0, %1, %2" : "=v"(r) : "v"(lo), "v"(hi));
  return r;
}

#define GLD16(gp, lp) __builtin_amdgcn_global_load_lds(                      \
    (__attribute__((address_space(1))) void*)(void*)(gp),                    \
    (__attribute__((address_space(3))) void*)(lp), 16, 0, 0)

// log2(e) * (1/sqrt(HD))  folded into Q at projection time
#define QSCALE 0.1803368801111244f

// ---------------- fused prep: cvt_x + w transposes + rope table ----------------
__global__ void __launch_bounds__(256)
prep_kernel(const float* __restrict__ x, const float* __restrict__ wq,
            const float* __restrict__ wk, const float* __restrict__ wv,
            const float* __restrict__ wo,
            short* __restrict__ x_bf, short* __restrict__ wq_t,
            short* __restrict__ wk_t, short* __restrict__ wv_t,
            short* __restrict__ wo_t,
            float* __restrict__ ct, float* __restrict__ st) {
  __shared__ float t[32][33];
  int blk = blockIdx.x;
  const int tid = threadIdx.x;
  if (blk < 8192) {
    int i = blk * 256 + tid;
    f32x4 v = *reinterpret_cast<const f32x4*>(x + (size_t)i * 4);
    short4v o;
    o.x = f2bf(v.x); o.y = f2bf(v.y); o.z = f2bf(v.z); o.w = f2bf(v.w);
    *reinterpret_cast<short4v*>(x_bf + (size_t)i * 4) = o;
    return;
  }
  blk -= 8192;
  if (blk < 6144 || blk >= 6400) {
    const float* in; short* out; int C, bx, by;
    if (blk < 4096)      { in = wq; out = wq_t; C = 2048; bx = blk & 63; by = blk >> 6; }
    else if (blk < 5120) { int lo = blk - 4096; in = wk; out = wk_t; C = 512; bx = lo & 15; by = lo >> 4; }
    else if (blk < 6144) { int lo = blk - 5120; in = wv; out = wv_t; C = 512; bx = lo & 15; by = lo >> 4; }
    else                 { int lo = blk - 6400; in = wo; out = wo_t; C = 2048; bx = lo & 63; by = lo >> 6; }
    const int c0 = bx * 32, r0 = by * 32;
    const int tx = tid & 31, ty = tid >> 5;
#pragma unroll
    for (int j = 0; j < 32; j += 8)
      t[ty + j][tx] = in[(size_t)(r0 + ty + j) * C + c0 + tx];
    __syncthreads();
#pragma unroll
    for (int j = 0; j < 32; j += 8)
      out[(size_t)(c0 + ty + j) * DIM + r0 + tx] = f2bf(t[tx][ty + j]);
    return;
  }
  {
    int i = (blk - 6144) * 256 + tid;  // [0, 65536) = SEQ*32
    int pos = i >> 5, f = i & 31;
    float inv = powf(10000.0f, -(float)f / 32.0f);
    float th = (float)pos * inv;
    ct[i] = cosf(th);
    st[i] = sinf(th);
  }
}

// standalone wo transpose (fallback when workspace too small for separate wo_t)
__global__ void transpose_bf_kernel(const float* __restrict__ in, short* __restrict__ out,
                                    int R, int C) {
  __shared__ float t[32][33];
  int c0 = blockIdx.x * 32, r0 = blockIdx.y * 32;
  int tx = threadIdx.x, ty = threadIdx.y;  // (32, 8)
#pragma unroll
  for (int j = 0; j < 32; j += 8)
    t[ty + j][tx] = in[(size_t)(r0 + ty + j) * C + c0 + tx];
  __syncthreads();
#pragma unroll
  for (int j = 0; j < 32; j += 8)
    out[(size_t)(c0 + ty + j) * R + r0 + tx] = f2bf(t[tx][ty + j]);
}

// ---------------- pipelined GEMM mainloop (round-4/7 config, unpinned scheduler) ----
// 128x128 tile, BK=32, 4 waves (2x2), 3 LDS buffers (48 KB), stage t+2 while
// computing t, counted vmcnt(4) per tile, 16x16x32 MFMA.
// Swizzle: 16B-unit ^= (row>>1)&3 -> conflict-free (measured 0).
// NOTE: empty asm memory clobber after s_barrier (NOT sched_barrier(0)) —
// keeps staging writes from hoisting above the barrier (correctness) while
// leaving MFMA/VALU/ds_read scheduling free (m141: sched_barrier(0) pinning
// cost 874->510 TF on this structure).

__device__ __forceinline__ void mfma_tile(const short* __restrict__ as_,
                                          const short* __restrict__ bs_,
                                          int wr, int wc, int lg, int lr,
                                          f32x4 (&acc)[4][4]) {
  short8 af[4], bq[4];
#pragma unroll
  for (int mt = 0; mt < 4; ++mt) {
    int row = wr * 64 + mt * 16 + lr;
    af[mt] = *(const short8*)&as_[row * 32 + ((lg ^ ((row >> 1) & 3)) << 3)];
  }
#pragma unroll
  for (int nt = 0; nt < 4; ++nt) {
    int row = wc * 64 + nt * 16 + lr;
    bq[nt] = *(const short8*)&bs_[row * 32 + ((lg ^ ((row >> 1) & 3)) << 3)];
  }
  __builtin_amdgcn_s_setprio(1);
#pragma unroll
  for (int mt = 0; mt < 4; ++mt)
#pragma unroll
    for (int nt = 0; nt < 4; ++nt)
      acc[mt][nt] = __builtin_amdgcn_mfma_f32_16x16x32_bf16(af[mt], bq[nt], acc[mt][nt], 0, 0, 0);
  __builtin_amdgcn_s_setprio(0);
}

#define STAGE4(SA, SB) do {                                                  \
    GLD16(pA0, (SA) + w * 512);  GLD16(pA1, (SA) + 2048 + w * 512);          \
    GLD16(pB0, (SB) + w * 512);  GLD16(pB1, (SB) + 2048 + w * 512);          \
    pA0 += 32; pA1 += 32; pB0 += 32; pB1 += 32; } while (0)

#define TILE(CA, CB, SA, SB, DOSTAGE, VM) do {                               \
    asm volatile("s_waitcnt vmcnt(" VM ")" ::: "memory");                    \
    __builtin_amdgcn_s_barrier();                                            \
    asm volatile("" ::: "memory");                                           \
    if (DOSTAGE) { STAGE4(SA, SB); }                                         \
    mfma_tile(CA, CB, wr, wc, lg, lr, acc);                                  \
  } while (0)

// As/Bs: 3 buffers of 4096 shorts each (8 KB per buffer per operand)
__device__ __forceinline__ void gemm_mainloop(const short* __restrict__ A,
                                              const short* __restrict__ Bt,
                                              int m0, int n0,
                                              short* As, short* Bs,
                                              f32x4 (&acc)[4][4]) {
  const int tid = threadIdx.x;
  const int w = tid >> 6, l = tid & 63;
  const int lg = l >> 4, lr = l & 15;
  const int wr = w >> 1, wc = w & 1;
  // staging map: chunk c -> row=c>>2, 16B-unit u=c&3; source unit pre-swizzled
  const int c1 = tid + 256;
  const int r0 = tid >> 2, k0 = ((tid & 3) ^ ((r0 >> 1) & 3)) << 3;
  const int r1 = c1 >> 2,  k1 = ((c1 & 3) ^ ((r1 >> 1) & 3)) << 3;
  const short* pA0 = A + (size_t)(m0 + r0) * DIM + k0;
  const short* pA1 = A + (size_t)(m0 + r1) * DIM + k1;
  const short* pB0 = Bt + (size_t)(n0 + r0) * DIM + k0;
  const short* pB1 = Bt + (size_t)(n0 + r1) * DIM + k1;
  short* A0 = As;            short* B0 = Bs;
  short* A1 = As + 4096;     short* B1 = Bs + 4096;
  short* A2 = As + 8192;     short* B2 = Bs + 8192;

  // prologue: stage tiles 0 and 1
  STAGE4(A0, B0);
  STAGE4(A1, B1);

  // 64 K-tiles total: 20x3 main + 4 peeled
  for (int it = 0; it < 20; ++it) {
    TILE(A0, B0, A2, B2, true, "4");
    TILE(A1, B1, A0, B0, true, "4");
    TILE(A2, B2, A1, B1, true, "4");
  }
  TILE(A0, B0, A2, B2, true,  "4");  // t=60, stage t=62
  TILE(A1, B1, A0, B0, true,  "4");  // t=61, stage t=63
  TILE(A2, B2, A0, B0, false, "4");  // t=62
  TILE(A0, B0, A1, B1, false, "0");  // t=63
}

__device__ __forceinline__ int2 xcd_swizzle(int nwg) {
  int id = blockIdx.y * gridDim.x + blockIdx.x;
  int swz = (id & 7) * (nwg >> 3) + (id >> 3);
  return make_int2(swz % gridDim.x, swz / gridDim.x);
}

// ---------------- fused QKV projection ----------------
__global__ void __launch_bounds__(256, 3)
gemm_qkv_kernel(const short* __restrict__ A,
                const short* __restrict__ wqt, const short* __restrict__ wkt,
                const short* __restrict__ wvt,
                short* __restrict__ q_ws, short* __restrict__ k_ws, short* __restrict__ v_ws,
                const float* __restrict__ ct, const float* __restrict__ st) {
  __shared__ __align__(16) short As[12288];
  __shared__ __align__(16) short Bs[12288];
  int2 bxy = xcd_swizzle(24 * 32);
  const int n0g = bxy.x * 128;
  const int m0 = bxy.y * 128;
  int mode, n0;
  const short* Bt;
  short* outp;
  if (n0g < 2048)      { mode = 1; Bt = wqt; n0 = n0g;        outp = q_ws; }
  else if (n0g < 2560) { mode = 2; Bt = wkt; n0 = n0g - 2048; outp = k_ws; }
  else                 { mode = 3; Bt = wvt; n0 = n0g - 2560; outp = v_ws; }

  f32x4 acc[4][4] = {};
  gemm_mainloop(A, Bt, m0, n0, As, Bs, acc);

  const int tid = threadIdx.x;
  const int w = tid >> 6, l = tid & 63;
  const int lg = l >> 4, lr = l & 15;
  const int wr = w >> 1, wc = w & 1;
  const int mrow0 = m0 + wr * 64;
  const int ncol0 = n0 + wc * 64;
#pragma unroll
  for (int mt = 0; mt < 4; ++mt)
#pragma unroll
    for (int nt = 0; nt < 4; ++nt)
#pragma unroll
      for (int i = 0; i < 4; ++i) {
        int m = mrow0 + mt * 16 + lg * 4 + i;
        int n = ncol0 + nt * 16 + lr;
        float v = acc[mt][nt][i];
        int b = m >> 11, s = m & (SEQ - 1);
        int h = n >> 6, d = n & 63;
        if (mode == 3) {
          outp[((size_t)(b * NKV + h) * HD + d) * SEQ + s] = f2bf(v);
        } else {
          float p = __shfl_xor(v, 1);
          float cs = ct[(s << 5) + (d >> 1)];
          float sn = st[(s << 5) + (d >> 1)];
          float r = ((d & 1) == 0) ? (v * cs - p * sn) : (p * sn + v * cs);
          if (mode == 1) {
            r *= QSCALE;  // 1/sqrt(HD) * log2(e): softmax done in exp2 domain
            outp[((size_t)(b * NH + h) * SEQ + s) * HD + d] = f2bf(r);
          } else {
            outp[((size_t)(b * NKV + h) * SEQ + s) * HD + d] = f2bf(r);
          }
        }
      }
}

// ---------------- O projection (f32 out) ----------------
__global__ void __launch_bounds__(256, 3)
gemm_o_kernel(const short* __restrict__ A, const short* __restrict__ Bt,
              float* __restrict__ out) {
  __shared__ __align__(16) short As[12288];
  __shared__ __align__(16) short Bs[12288];
  int2 bxy = xcd_swizzle(16 * 32);
  const int m0 = bxy.y * 128, n0 = bxy.x * 128;
  f32x4 acc[4][4] = {};
  gemm_mainloop(A, Bt, m0, n0, As, Bs, acc);
  const int tid = threadIdx.x;
  const int w = tid >> 6, l = tid & 63;
  const int lg = l >> 4, lr = l & 15;
  const int wr = w >> 1, wc = w & 1;
#pragma unroll
  for (int mt = 0; mt < 4; ++mt)
#pragma unroll
    for (int nt = 0; nt < 4; ++nt)
#pragma unroll
      for (int i = 0; i < 4; ++i) {
        int m = m0 + wr * 64 + mt * 16 + lg * 4 + i;
        int n = n0 + wc * 64 + nt * 16 + lr;
        out[(size_t)m * DIM + n] = acc[mt][nt][i];
      }
}

// ---------------- flash attention (swapped QK^T, GQA, causal, exp2 domain) ----------------
// Q: [b][h][s][d] bf16 (pre-scaled by QSCALE), K: [b][kvh][s][d], V: [b][kvh][d][s]
// O: [b][s][h*HD+d] bf16
// 1024 blocks (grid 16x32x2); each processes q-tiles {x, 31-x} = 33 KV tiles.
__global__ void __launch_bounds__(256, 3)
attn_fwd_kernel(const short* __restrict__ Q, const short* __restrict__ K,
                const short* __restrict__ V, short* __restrict__ O) {
  __shared__ __align__(16) short Ks[3][4096];  // [64 keys][64 dims], xor-swizzled
  __shared__ __align__(16) short Vs[3][4096];  // [64 dims][64 keys], xor-swizzled
  const int tid = threadIdx.x;
  const int w = tid >> 6, l = tid & 63;
  const int lg = l >> 4, lr = l & 15;
  const int h = blockIdx.y;
  const int b = blockIdx.z;
  const int kvh = h >> 2;
  const int lh = lg >> 1, sub = (lg & 1) << 2;

  const short* kbase = K + (size_t)(b * NKV + kvh) * SEQ * HD;
  const short* vbase = V + (size_t)(b * NKV + kvh) * HD * SEQ;

  const int c1 = tid + 256;
  const int r0 = tid >> 3, e0 = ((tid & 7) ^ (r0 & 7)) << 3;
  const int r1 = c1 >> 3, e1 = ((c1 & 7) ^ (r1 & 7)) << 3;

  short8 ones;
#pragma unroll
  for (int i = 0; i < 8; ++i) ones[i] = (short)0x3F80;  // bf16 1.0

#define ASTAGE(kvt, KB, VB) do { const int kv_ = (kvt) * 64;                  \
    GLD16(kbase + (size_t)(kv_ + r0) * HD + e0, (KB) + w * 512);              \
    GLD16(kbase + (size_t)(kv_ + r1) * HD + e1, (KB) + 2048 + w * 512);       \
    GLD16(vbase + (size_t)r0 * SEQ + kv_ + e0, (VB) + w * 512);               \
    GLD16(vbase + (size_t)r1 * SEQ + kv_ + e1, (VB) + 2048 + w * 512); } while (0)

  for (int qi = 0; qi < 2; ++qi) {
    const int qblk = (qi == 0) ? (int)blockIdx.x : (31 - (int)blockIdx.x);
    const int q0 = qblk * 64;
    const int qrow = q0 + w * 16 + lr;  // this lane's q column (swapped layout)

    const short* qptr = Q + ((size_t)(b * NH + h) * SEQ + qrow) * HD;
    short8 qf0 = *(const short8*)(qptr + (lg << 3));
    short8 qf1 = *(const short8*)(qptr + 32 + (lg << 3));

    float m_run = 0.f;       // running max in log2 domain (defer-max; 0-seed is safe)
    f32x4 oacc[4] = {};
    f32x4 lacc = {};         // row-sums, same row layout as oacc

    short* kb0 = Ks[0]; short* kb1 = Ks[1]; short* kb2 = Ks[2];
    short* vb0 = Vs[0]; short* vb1 = Vs[1]; short* vb2 = Vs[2];

    ASTAGE(0, kb0, vb0);
    if (qblk >= 1) ASTAGE(1, kb1, vb1);

    for (int t = 0; t <= qblk; ++t) {
      if (t < qblk) asm volatile("s_waitcnt vmcnt(4)" ::: "memory");
      else          asm volatile("s_waitcnt vmcnt(0)" ::: "memory");
      __builtin_amdgcn_s_barrier();
      asm volatile("" ::: "memory");
      if (t + 2 <= qblk) ASTAGE(t + 2, kb2, vb2);

      const short* ks = kb0;
      const short* vs = vb0;
      const int kv0 = t * 64;

      // hoist all K fragments (8 x b128) and V fragments (16 x b64)
      short8 ka[4][2];
#pragma unroll
      for (int t4 = 0; t4 < 4; ++t4) {
        int row = t4 * 16 + lr, rx = row & 7;
        ka[t4][0] = *(const short8*)&ks[row * 64 + ((lg ^ rx) << 3)];
        ka[t4][1] = *(const short8*)&ks[row * 64 + (((4 + lg) ^ rx) << 3)];
      }
      short8 vbf[4][2];
#pragma unroll
      for (int nt = 0; nt < 4; ++nt) {
        int row = nt * 16 + lr, rx = row & 7;
#pragma unroll
        for (int ks_ = 0; ks_ < 2; ++ks_) {
          union { short8 s8; short4v hh[2]; } u;
          u.hh[0] = *(const short4v*)&vs[row * 64 + (((4 * ks_ + lh) ^ rx) << 3) + sub];
          u.hh[1] = *(const short4v*)&vs[row * 64 + (((4 * ks_ + 2 + lh) ^ rx) << 3) + sub];
          vbf[nt][ks_] = u.s8;
        }
      }

      // S' = K*Q - m_run  (C seeded with -m_run; col=q matches lane layout)
      f32x4 sacc[4];
      {
        f32x4 seed;
        seed[0] = -m_run; seed[1] = -m_run; seed[2] = -m_run; seed[3] = -m_run;
        __builtin_amdgcn_s_setprio(1);
#pragma unroll
        for (int t4 = 0; t4 < 4; ++t4) {
          f32x4 z = __builtin_amdgcn_mfma_f32_16x16x32_bf16(ka[t4][0], qf0, seed, 0, 0, 0);
          sacc[t4] = __builtin_amdgcn_mfma_f32_16x16x32_bf16(ka[t4][1], qf1, z, 0, 0, 0);
        }
        __builtin_amdgcn_s_setprio(0);
      }

      if (t == qblk) {  // diagonal tile: causal mask
#pragma unroll
        for (int t4 = 0; t4 < 4; ++t4)
#pragma unroll
          for (int i = 0; i < 4; ++i)
            if (kv0 + t4 * 16 + lg * 4 + i > qrow) sacc[t4][i] = -__builtin_inff();
      }

      // tile max in shifted domain (max3-friendly triplet tree)
      float a0 = fmaxf(fmaxf(sacc[0][0], sacc[0][1]), sacc[0][2]);
      float a1 = fmaxf(fmaxf(sacc[0][3], sacc[1][0]), sacc[1][1]);
      float a2 = fmaxf(fmaxf(sacc[1][2], sacc[1][3]), sacc[2][0]);
      float a3 = fmaxf(fmaxf(sacc[2][1], sacc[2][2]), sacc[2][3]);
      float a4 = fmaxf(fmaxf(sacc[3][0], sacc[3][1]), sacc[3][2]);
      float tm = fmaxf(fmaxf(fmaxf(a0, a1), a2), fmaxf(fmaxf(a3, a4), sacc[3][3]));
      tm = fmaxf(tm, __shfl_xor(tm, 16));
      tm = fmaxf(tm, __shfl_xor(tm, 32));

      // defer-max: rescale only when shifted max exceeds THR (P <= 2^12 otherwise)
      if (!__all(tm <= 12.0f)) {
        float d = fmaxf(tm, 0.f);
        float alpha = EXP2(-d);
        float av0 = __shfl(alpha, (lg << 2));
        float av1 = __shfl(alpha, (lg << 2) | 1);
        float av2 = __shfl(alpha, (lg << 2) | 2);
        float av3 = __shfl(alpha, (lg << 2) | 3);
#pragma unroll
        for (int nt = 0; nt < 4; ++nt) {
          oacc[nt][0] *= av0; oacc[nt][1] *= av1;
          oacc[nt][2] *= av2; oacc[nt][3] *= av3;
        }
        lacc[0] *= av0; lacc[1] *= av1; lacc[2] *= av2; lacc[3] *= av3;
        m_run += d;
#pragma unroll
        for (int t4 = 0; t4 < 4; ++t4)
#pragma unroll
          for (int i = 0; i < 4; ++i) sacc[t4][i] -= d;
      }

      // P = exp2(S') packed straight to bf16 fragments (k-bijection feeds PV A)
      union { short8 s8; uint32_t u[4]; } pa0, pa1;
      pa0.u[0] = cvtpk_bf16(EXP2(sacc[0][0]), EXP2(sacc[0][1]));
      pa0.u[1] = cvtpk_bf16(EXP2(sacc[0][2]), EXP2(sacc[0][3]));
      pa0.u[2] = cvtpk_bf16(EXP2(sacc[1][0]), EXP2(sacc[1][1]));
      pa0.u[3] = cvtpk_bf16(EXP2(sacc[1][2]), EXP2(sacc[1][3]));
      pa1.u[0] = cvtpk_bf16(EXP2(sacc[2][0]), EXP2(sacc[2][1]));
      pa1.u[1] = cvtpk_bf16(EXP2(sacc[2][2]), EXP2(sacc[2][3]));
      pa1.u[2] = cvtpk_bf16(EXP2(sacc[3][0]), EXP2(sacc[3][1]));
      pa1.u[3] = cvtpk_bf16(EXP2(sacc[3][2]), EXP2(sacc[3][3]));

      // O += P * V; l += P * ones  (row-sum via MFMA, replaces lsum adds + shfls)
      __builtin_amdgcn_s_setprio(1);
#pragma unroll
      for (int nt = 0; nt < 4; ++nt) {
        oacc[nt] = __builtin_amdgcn_mfma_f32_16x16x32_bf16(pa0.s8, vbf[nt][0], oacc[nt], 0, 0, 0);
        oacc[nt] = __builtin_amdgcn_mfma_f32_16x16x32_bf16(pa1.s8, vbf[nt][1], oacc[nt], 0, 0, 0);
      }
      lacc = __builtin_amdgcn_mfma_f32_16x16x32_bf16(pa0.s8, ones, lacc, 0, 0, 0);
      lacc = __builtin_amdgcn_mfma_f32_16x16x32_bf16(pa1.s8, ones, lacc, 0, 0, 0);
      __builtin_amdgcn_s_setprio(0);

      short* tk = kb0; kb0 = kb1; kb1 = kb2; kb2 = tk;
      short* tv = vb0; vb0 = vb1; vb1 = vb2; vb2 = tv;
    }

    // epilogue: normalize and store (l already in oacc row layout, no shfl)
    float linv0 = 1.f / lacc[0], linv1 = 1.f / lacc[1];
    float linv2 = 1.f / lacc[2], linv3 = 1.f / lacc[3];
#pragma unroll
    for (int nt = 0; nt < 4; ++nt) {
      int d = nt * 16 + lr;
      int qb = q0 + w * 16 + lg * 4;
      O[(size_t)(b * SEQ + qb + 0) * DIM + h * HD + d] = f2bf(oacc[nt][0] * linv0);
      O[(size_t)(b * SEQ + qb + 1) * DIM + h * HD + d] = f2bf(oacc[nt][1] * linv1);
      O[(size_t)(b * SEQ + qb + 2) * DIM + h * HD + d] = f2bf(oacc[nt][2] * linv2);
      O[(size_t)(b * SEQ + qb + 3) * DIM + h * HD + d] = f2bf(oacc[nt][3] * linv3);
    }
    __syncthreads();  // protect LDS buffers before next q-tile's prologue staging
  }
#undef ASTAGE
}

// ---------------- launch ----------------

extern "C" void kernel_launch(void* const* d_in, const int* in_sizes, int n_in,
                              void* d_out, int out_size, void* d_ws, size_t ws_size,
                              hipStream_t stream) {
  const float* x  = (const float*)d_in[0];
  const float* wq = (const float*)d_in[1];
  const float* wk = (const float*)d_in[2];
  const float* wv = (const float*)d_in[3];
  const float* wo = (const float*)d_in[4];
  float* out = (float*)d_out;
  char* ws = (char*)d_ws;

  short* x_bf  = (short*)(ws + 0);          // 16 MB  [4096][2048]
  short* attn  = (short*)(ws + 0);          // alias of x_bf (dead after QKV GEMM)
  short* q_ws  = (short*)(ws + 16777216);   // 16 MB  [b][h][s][d]
  short* k_ws  = (short*)(ws + 33554432);   // 4 MB   [b][kvh][s][d]
  short* v_ws  = (short*)(ws + 37748736);   // 4 MB   [b][kvh][d][s]
  short* wq_t  = (short*)(ws + 41943040);   // 8 MB   [N][K]
  short* wk_t  = (short*)(ws + 50331648);   // 2 MB
  short* wv_t  = (short*)(ws + 52428800);   // 2 MB
  float* ct    = (float*)(ws + 54525952);   // 256 KB
  float* st    = (float*)(ws + 54788096);   // 256 KB
  // fast path: dedicated wo_t (8 MB) so the wo transpose fuses into prep
  const int sep_wo = (ws_size >= (size_t)63438848);
  short* wo_t  = sep_wo ? (short*)(ws + 55050240) : wq_t;  // alias wq_t in fallback
  (void)in_sizes; (void)n_in; (void)out_size;

  // fused prep: cvt_x + wq/wk/wv (+wo when sep) transposes + rope table
  prep_kernel<<<sep_wo ? 18688 : 14592, 256, 0, stream>>>(
      x, wq, wk, wv, wo, x_bf, wq_t, wk_t, wv_t, wo_t, ct, st);

  gemm_qkv_kernel<<<dim3(24, 32), 256, 0, stream>>>(x_bf, wq_t, wk_t, wv_t,
                                                    q_ws, k_ws, v_ws, ct, st);

  if (!sep_wo)  // fallback: wo transpose after qkv (wo_t aliases wq_t)
    transpose_bf_kernel<<<dim3(64, 64), dim3(32, 8), 0, stream>>>(wo, wo_t, DIM, 2048);

  attn_fwd_kernel<<<dim3(16, 32, 2), 256, 0, stream>>>(q_ws, k_ws, v_ws, attn);

  gemm_o_kernel<<<dim3(16, 32), 256, 0, stream>>>(attn, wo_t, out);
}